// Round 8
// baseline (300.156 us; speedup 1.0000x reference)
//
#include <hip/hip_runtime.h>

// PadWithin: out[b,c,2i,2j] = feats[b,c,i,j], all other entries zero.
// feats: (16,64,128,128) fp32 -> out: (16,64,256,256) fp32.
//
// Session accounting (closed): timed region = poison fill (~167 us) +
// hidden reset dispatches (~65 us, measured via R4 probe residual) +
// kernel. Kernel ladder: one-shot=70us, loop x16=79, decoupled loop=82,
// one-shot + NT LOAD = 66us (R7, best). Mechanism: the read stream
// allocating in per-XCD L2 evicts dirty store lines (read-free fill does
// 6.4 TB/s on this same buffer; mixed streams plateau ~5). nt-load
// recovers part of it.
//
// R8 change (single): 2 row-pairs per wave, STRAIGHT-LINE (no loop —
// every loop structure lost to one-shot). Per wave: 2 nt f2 loads issued
// back-to-back, 2 dependency-free zero-row stores (flow during load
// flight), 2 data stores. All stores dense 1 KiB/wave; wave count and
// load-instruction count halve vs R7.

#define IN_W 128

typedef float f2 __attribute__((ext_vector_type(2)));
typedef float f4 __attribute__((ext_vector_type(4)));

__global__ __launch_bounds__(256) void pad_within_kernel(
    const float* __restrict__ in, float* __restrict__ out) {
    const unsigned lane = threadIdx.x & 63u;
    const unsigned wid  = (blockIdx.x * blockDim.x + threadIdx.x) >> 6;
    const unsigned p0   = wid * 2u;           // first of 2 consecutive row-pairs

    const f2* irow  = (const f2*)(in + (size_t)p0 * IN_W) + lane;  // 64 f2/row
    f4*       opair = (f4*)(out + (size_t)p0 * 512) + lane;        // 128 f4/pair

    // two independent nt loads (rows p0, p0+1), both in flight together
    f2 a = __builtin_nontemporal_load(irow);
    f2 b = __builtin_nontemporal_load(irow + 64);

    // zero rows: no data dependency -> store pipe busy during load flight
    const f4 zero = {0.f, 0.f, 0.f, 0.f};
    opair[64]  = zero;   // odd row of pair p0
    opair[192] = zero;   // odd row of pair p0+1

    // data rows as loads retire
    opair[0]   = (f4){a.x, 0.f, a.y, 0.f};
    opair[128] = (f4){b.x, 0.f, b.y, 0.f};
}

extern "C" void kernel_launch(void* const* d_in, const int* in_sizes, int n_in,
                              void* d_out, int out_size, void* d_ws, size_t ws_size,
                              hipStream_t stream) {
    const float* feats = (const float*)d_in[0];
    float* out = (float*)d_out;
    // 131072 row-pairs / 2 per wave = 65536 waves = 16384 blocks of 256.
    dim3 block(256);
    dim3 grid(16384);
    pad_within_kernel<<<grid, block, 0, stream>>>(feats, out);
}

// Round 9
// 297.669 us; speedup vs baseline: 1.0084x; 1.0084x over previous
//
#include <hip/hip_runtime.h>

// PadWithin: out[b,c,2i,2j] = feats[b,c,i,j], all other entries zero.
// feats: (16,64,128,128) fp32 -> out: (16,64,256,256) fp32.
//
// FINAL (session-best, R7 = 297.3 us total). Timed-region accounting,
// closed via the R4 4x-pass probe:
//   ~166 us  harness poison fill (1.07 GB @ 6.45 TB/s)  [untouchable]
//   ~65 us   hidden reset dispatches (R4 residual)       [untouchable]
//   ~66 us   this kernel: 335 MB @ ~5.1 TB/s effective
// Kernel ladder: loop x16=79, decoupled x8=82, one-shot=70, 2-pair
// straight-line=69, one-shot + NT-LOAD = 66 (best). Mechanism: the input
// read stream allocating in per-XCD L2 evicts dirty store lines (read-free
// fill hits 6.4 TB/s on this very buffer; mixed streams plateau ~5).
// __builtin_nontemporal_load bypasses that allocation -> only structural
// lever that produced a measurable win (+6%).
//
// Structure: one wave per input row = output row-pair (2 KiB contiguous):
//   lane: nt f2 load; dependency-free zero store to odd row (issues during
//   load flight); {x,0,y,0} store to even row. All stores dense 1 KiB/wave.

#define IN_W 128

typedef float f2 __attribute__((ext_vector_type(2)));
typedef float f4 __attribute__((ext_vector_type(4)));

__global__ __launch_bounds__(256) void pad_within_kernel(
    const float* __restrict__ in, float* __restrict__ out) {
    const unsigned lane = threadIdx.x & 63u;
    const unsigned wid  = (blockIdx.x * blockDim.x + threadIdx.x) >> 6;  // row-pair

    const f2* irow  = (const f2*)(in + (size_t)wid * IN_W) + lane;   // 512 B/wave
    f4*       opair = (f4*)(out + (size_t)wid * 512) + lane;         // 2 KiB/pair

    // nt load: bypass L2 allocation (input is L3-resident; never re-read)
    f2 x = __builtin_nontemporal_load(irow);

    // odd output row: no dependency -> store pipe stays busy during load
    opair[64] = (f4){0.f, 0.f, 0.f, 0.f};

    // even output row: {x,0,y,0} once the load retires
    opair[0] = (f4){x.x, 0.f, x.y, 0.f};
}

extern "C" void kernel_launch(void* const* d_in, const int* in_sizes, int n_in,
                              void* d_out, int out_size, void* d_ws, size_t ws_size,
                              hipStream_t stream) {
    const float* feats = (const float*)d_in[0];
    float* out = (float*)d_out;
    // 16*64*128 = 131072 row-pairs = 131072 waves = 32768 blocks of 256.
    dim3 block(256);
    dim3 grid(32768);
    pad_within_kernel<<<grid, block, 0, stream>>>(feats, out);
}